// Round 3
// baseline (358.728 us; speedup 1.0000x reference)
//
#include <hip/hip_runtime.h>

#define NNEUR 4096      // N_NEURONS == BATCH
#define FEATN 512
#define LRC   0.005f
#define NBLK  256       // k_front grid size (== CU count; all blocks co-resident)
// 2*SIGMA^2 = 8 ; 2*FEAT = 1024

// ---------------- ws layout (bytes) ----------------
// 0     : sumx[4096]    (batch-mean of sensory, pre-scaled 1/4096)
// 16384 : current[512]
// 18432 : outff[512]
// 20480 : feat[512]
// 22528 : bmuKey (ull)
// 22592 : bar[8]  (4 counters + 4 flags, zeroed by hipMemsetAsync)
// 24576 : partial[64*4096] floats (1 MB colsum partials)

// Device-scope grid barrier: fresh counter+flag per barrier index (no reuse,
// so no sense-reversal races). All NBLK blocks are co-resident (256 blocks,
// <64 VGPR, 0 LDS => capacity ~8 blocks/CU), so the spin cannot deadlock.
__device__ __forceinline__ void gbar(unsigned* bar, int k) {
    __syncthreads();
    if (threadIdx.x == 0) {
        __threadfence();                                   // release prior writes (agent scope)
        unsigned prev = atomicAdd(&bar[k], 1u);            // device-scope by default
        if (prev == NBLK - 1u) {
            __hip_atomic_store(&bar[4 + k], 1u, __ATOMIC_RELEASE, __HIP_MEMORY_SCOPE_AGENT);
        } else {
            while (__hip_atomic_load(&bar[4 + k], __ATOMIC_ACQUIRE, __HIP_MEMORY_SCOPE_AGENT) == 0u)
                __builtin_amdgcn_s_sleep(2);
        }
        __threadfence();                                   // acquire others' writes
    }
    __syncthreads();
}

// Fused front-end: colsum partials -> fold+init -> current -> outff -> feat.
// grid NBLK=256, block 256.
__global__ __launch_bounds__(256) void k_front(
        const float* __restrict__ A,     const float* __restrict__ Win,
        const float* __restrict__ Wout,  const float* __restrict__ projW,
        const float* __restrict__ projb,
        float* __restrict__ sumx, float* __restrict__ cur, float* __restrict__ outff,
        float* __restrict__ feat, float* __restrict__ partial,
        unsigned* __restrict__ bar, unsigned long long* __restrict__ bmuKey) {
    const int b = blockIdx.x, tid = threadIdx.x;

    // ---- Phase 0: partial column sums of A [4096 x 4096] ----
    // block b: colgroup = b&3 (1024 cols), rowchunk = b>>2 (64 rows)
    {
        int col = (b & 3) * 1024 + tid * 4;
        const float* p = A + (size_t)(b >> 2) * 64 * NNEUR + col;
        float4 acc = make_float4(0.f, 0.f, 0.f, 0.f);
        for (int r = 0; r < 64; r += 8) {
            #pragma unroll
            for (int u = 0; u < 8; ++u) {
                float4 v = *reinterpret_cast<const float4*>(p + (size_t)(r + u) * NNEUR);
                acc.x += v.x; acc.y += v.y; acc.z += v.z; acc.w += v.w;
            }
        }
        *reinterpret_cast<float4*>(partial + (size_t)(b >> 2) * NNEUR + col) = acc;
    }
    gbar(bar, 0);

    // ---- Phase 1: fold 64 partials -> sumx (scaled); init accumulators ----
    if (b < 16) {
        int col = b * 256 + tid;
        float acc = 0.f;
        #pragma unroll 8
        for (int p = 0; p < 64; ++p)
            acc += partial[(size_t)p * NNEUR + col];
        sumx[col] = acc * (1.0f / 4096.0f);
    } else if (b == 16) { cur[tid] = 0.f;   cur[tid + 256] = 0.f; }
    else if (b == 17)   { outff[tid] = 0.f; outff[tid + 256] = 0.f; }
    else if (b == 18 && tid == 0) *bmuKey = ~0ull;
    gbar(bar, 1);

    // ---- Phase 2: current[t] = sum_i sumx[i]*Win[i][t] ----
    {
        int r0 = b * 16;
        float a0 = 0.f, a1 = 0.f;
        #pragma unroll 4
        for (int i = 0; i < 16; ++i) {
            float s = sumx[r0 + i];
            const float* row = Win + (size_t)(r0 + i) * FEATN;
            a0 += s * row[tid];
            a1 += s * row[tid + 256];
        }
        atomicAdd(&cur[tid], a0);
        atomicAdd(&cur[tid + 256], a1);
    }
    gbar(bar, 2);

    // ---- Phase 3: outff[t] = sum_k (current[k]>=1)*Wout[k][t] ----
    if (b < 128) {
        int k0 = b * 4;
        float a0 = 0.f, a1 = 0.f;
        #pragma unroll
        for (int i = 0; i < 4; ++i) {
            if (cur[k0 + i] >= 1.0f) {                    // block-uniform branch
                const float* row = Wout + (size_t)(k0 + i) * FEATN;
                a0 += row[tid];
                a1 += row[tid + 256];
            }
        }
        atomicAdd(&outff[tid], a0);
        atomicAdd(&outff[tid + 256], a1);
    }
    gbar(bar, 3);

    // ---- Phase 4: feat[j] = relu(dot(projW[j,:], outff) + projb[j]) ----
    if (b < 128) {
        int lane = tid & 63;
        int j = b * 4 + (tid >> 6);
        const float4* row = reinterpret_cast<const float4*>(projW + (size_t)j * FEATN);
        const float4* v   = reinterpret_cast<const float4*>(outff);
        float4 a0 = row[lane],      b0 = v[lane];
        float4 a1 = row[lane + 64], b1 = v[lane + 64];
        float s = a0.x * b0.x + a0.y * b0.y + a0.z * b0.z + a0.w * b0.w
                + a1.x * b1.x + a1.y * b1.y + a1.z * b1.z + a1.w * b1.w;
        #pragma unroll
        for (int k = 32; k >= 1; k >>= 1) s += __shfl_xor(s, k, 64);
        if (lane == 0) {
            float f = s + projb[j];
            feat[j] = f > 0.f ? f : 0.f;
        }
    }
}

// d2[m] = ||som_w[m,:] - feat||^2, 8 rows/wave (16 dwordx4 in flight before any
// reduce). d2 -> d_out; grid argmin via encoded atomicMin. grid 2048, block 256.
__global__ void k_d2(const float* __restrict__ somw, const float* __restrict__ feat,
                     float* __restrict__ d2out, unsigned long long* __restrict__ bmuKey) {
    __shared__ float sf[FEATN];
    __shared__ unsigned long long smin[4];
    int tid = threadIdx.x;
    sf[tid]       = feat[tid];
    sf[tid + 256] = feat[tid + 256];
    __syncthreads();

    int wave = tid >> 6, lane = tid & 63;
    int base = blockIdx.x * 32 + wave * 8;
    const float4* fv = reinterpret_cast<const float4*>(sf);
    float4 f0 = fv[lane], f1 = fv[lane + 64];

    float4 va[8], vb[8];
    #pragma unroll
    for (int r = 0; r < 8; ++r) {
        const float4* row = reinterpret_cast<const float4*>(somw + (size_t)(base + r) * FEATN);
        va[r] = row[lane];
        vb[r] = row[lane + 64];
    }

    float s[8];
    #pragma unroll
    for (int r = 0; r < 8; ++r) {
        float d, acc = 0.f;
        d = va[r].x - f0.x; acc += d * d;
        d = va[r].y - f0.y; acc += d * d;
        d = va[r].z - f0.z; acc += d * d;
        d = va[r].w - f0.w; acc += d * d;
        d = vb[r].x - f1.x; acc += d * d;
        d = vb[r].y - f1.y; acc += d * d;
        d = vb[r].z - f1.z; acc += d * d;
        d = vb[r].w - f1.w; acc += d * d;
        s[r] = acc;
    }
    #pragma unroll
    for (int r = 0; r < 8; ++r) {
        #pragma unroll
        for (int k = 32; k >= 1; k >>= 1) s[r] += __shfl_xor(s[r], k, 64);
    }

    if (lane == 0) {
        *reinterpret_cast<float4*>(d2out + base)     = make_float4(s[0], s[1], s[2], s[3]);
        *reinterpret_cast<float4*>(d2out + base + 4) = make_float4(s[4], s[5], s[6], s[7]);
        unsigned long long kmin = ~0ull;
        #pragma unroll
        for (int r = 0; r < 8; ++r) {
            unsigned long long key =
                ((unsigned long long)__float_as_uint(s[r]) << 32) | (unsigned)(base + r);
            if (key < kmin) kmin = key;
        }
        smin[wave] = kmin;
    }
    __syncthreads();
    if (tid == 0) {
        unsigned long long k0 = smin[0];
        if (smin[1] < k0) k0 = smin[1];
        if (smin[2] < k0) k0 = smin[2];
        if (smin[3] < k0) k0 = smin[3];
        if (k0 < *(volatile unsigned long long*)bmuKey)
            atomicMin(bmuKey, k0);
    }
}

// out[m] = exp(-d2[m]*(1-LR*nb(m))^6 / 1024). BMU invariant across the 3
// reference iterations (bmu's d2 shrinks by the strictly smallest factor).
__global__ void k_final(float* __restrict__ out, const unsigned long long* __restrict__ bmuKey) {
    int m = blockIdx.x * 256 + threadIdx.x;
    unsigned long long key = *bmuKey;
    int bmu = (int)(key & 0xFFFFFFFFull);
    float dy = (float)(m >> 8)  - (float)(bmu >> 8);
    float dx = (float)(m & 255) - (float)(bmu & 255);
    float g2 = dy * dy + dx * dx;
    float nb = expf(-g2 * 0.125f);          // 2*SIGMA^2 = 8
    float fac = 1.0f - LRC * nb;
    float f2 = fac * fac;
    float f6 = f2 * f2 * f2;                // 3 iterations -> (1-LR*nb)^6 on d2
    float d2 = out[m];
    out[m] = expf(-(d2 * f6) * (1.0f / 1024.0f));   // 2*FEAT = 1024
}

extern "C" void kernel_launch(void* const* d_in, const int* in_sizes, int n_in,
                              void* d_out, int out_size, void* d_ws, size_t ws_size,
                              hipStream_t stream) {
    (void)in_sizes; (void)n_in; (void)out_size; (void)ws_size;
    const float* sensory = (const float*)d_in[0];
    const float* Win     = (const float*)d_in[1];
    const float* Wout    = (const float*)d_in[2];
    const float* projW   = (const float*)d_in[3];
    const float* projb   = (const float*)d_in[4];
    const float* somw    = (const float*)d_in[5];
    float* out = (float*)d_out;

    char* ws = (char*)d_ws;
    float* sumx    = (float*)(ws);
    float* cur     = (float*)(ws + 16384);
    float* outff   = (float*)(ws + 18432);
    float* feat    = (float*)(ws + 20480);
    unsigned long long* bmuKey = (unsigned long long*)(ws + 22528);
    unsigned* bar  = (unsigned*)(ws + 22592);
    float* partial = (float*)(ws + 24576);

    hipMemsetAsync(bar, 0, 32, stream);     // zero barrier counters/flags

    hipLaunchKernelGGL(k_front, dim3(NBLK), dim3(256), 0, stream,
                       sensory, Win, Wout, projW, projb,
                       sumx, cur, outff, feat, partial, bar, bmuKey);
    hipLaunchKernelGGL(k_d2,    dim3(2048), dim3(256), 0, stream, somw, feat, out, bmuKey);
    hipLaunchKernelGGL(k_final, dim3(256),  dim3(256), 0, stream, out, bmuKey);
}

// Round 4
// 270.077 us; speedup vs baseline: 1.3282x; 1.3282x over previous
//
#include <hip/hip_runtime.h>

#define NNEUR 4096      // N_NEURONS == BATCH
#define FEATN 512
#define LRC   0.005f
#define CHUNKS 256      // colsum partial chunks (16 rows each)
// 2*SIGMA^2 = 8 ; 2*FEAT = 1024

// ---------------- ws layout (bytes) ----------------
// 0     : sumx[4096]   (batch-mean of sensory, pre-scaled 1/4096; atomic fold)
// 16384 : current[512]
// 18432 : outff[512]
// 20480 : feat[512]
// 22528 : bmuKey (ull)
// 24576 : partial[CHUNKS*4096] floats (4 MB colsum partials)

// K1: partial column sums of sensory [4096 x 4096]; grid (4, CHUNKS), block 256.
// Block (bx,by) sums rows [by*16, by*16+16) for cols bx*1024 + tid*4 .. +3.
// Spare duty: designated blocks zero sumx / cur / outff / bmuKey for later
// kernels (safe: nothing reads them until after K1 completes in stream order).
__global__ void k_colsum(const float* __restrict__ A, float* __restrict__ partial,
                         float* __restrict__ sumx, float* __restrict__ cur,
                         float* __restrict__ outff, unsigned long long* __restrict__ bmuKey) {
    int tid = threadIdx.x;
    int col = blockIdx.x * 1024 + tid * 4;
    const float* p = A + (size_t)blockIdx.y * 16 * NNEUR + col;
    float4 acc = make_float4(0.f, 0.f, 0.f, 0.f);
    #pragma unroll
    for (int r = 0; r < 16; ++r) {
        float4 v = *reinterpret_cast<const float4*>(p + (size_t)r * NNEUR);
        acc.x += v.x; acc.y += v.y; acc.z += v.z; acc.w += v.w;
    }
    *reinterpret_cast<float4*>(partial + (size_t)blockIdx.y * NNEUR + col) = acc;

    if (blockIdx.x == 0) {
        if (blockIdx.y == 0) {
            // zero sumx[4096]
            float4 z = make_float4(0.f, 0.f, 0.f, 0.f);
            *reinterpret_cast<float4*>(sumx + tid * 4)        = z;
            *reinterpret_cast<float4*>(sumx + 1024 + tid * 4) = z;
            *reinterpret_cast<float4*>(sumx + 2048 + tid * 4) = z;
            *reinterpret_cast<float4*>(sumx + 3072 + tid * 4) = z;
        } else if (blockIdx.y == 1) {
            cur[tid] = 0.f; cur[tid + 256] = 0.f;
            outff[tid] = 0.f; outff[tid + 256] = 0.f;
            if (tid == 0) *bmuKey = ~0ull;
        }
    }
}

// K2: fold CHUNKS partials -> sumx (scaled 1/4096). grid (16, 8), block 256.
// Block (bx,by): cols bx*256+tid, chunks by*32..+32; atomicAdd (8-way contention).
__global__ void k_fold(const float* __restrict__ partial, float* __restrict__ sumx) {
    int col = blockIdx.x * 256 + threadIdx.x;
    const float* p = partial + (size_t)blockIdx.y * 32 * NNEUR + col;
    float acc = 0.f;
    #pragma unroll 8
    for (int c = 0; c < 32; ++c)
        acc += p[(size_t)c * NNEUR];
    atomicAdd(&sumx[col], acc * (1.0f / 4096.0f));
}

// K3: current[t] = sum_i sumx[i] * W_in[i][t]. grid (64,2), block 256.
__global__ void k_current(const float* __restrict__ Win, const float* __restrict__ sumx,
                          float* __restrict__ cur) {
    int t  = blockIdx.y * 256 + threadIdx.x;
    int i0 = blockIdx.x * 64;
    float acc = 0.f;
    #pragma unroll 8
    for (int i = 0; i < 64; ++i)
        acc += sumx[i0 + i] * Win[(size_t)(i0 + i) * FEATN + t];
    atomicAdd(&cur[t], acc);
}

// K4: outff[t] = sum_k (current[k] >= 1) * W_out[k][t]. grid (16,2), block 256.
__global__ void k_outff(const float* __restrict__ Wout, const float* __restrict__ cur,
                        float* __restrict__ outff) {
    int t  = blockIdx.y * 256 + threadIdx.x;
    int k0 = blockIdx.x * 32;
    float acc = 0.f;
    for (int k = 0; k < 32; ++k) {
        if (cur[k0 + k] >= 1.0f)            // block-uniform branch
            acc += Wout[(size_t)(k0 + k) * FEATN + t];
    }
    atomicAdd(&outff[t], acc);
}

// K5: feat[j] = relu(dot(projW[j,:], outff) + projb[j]); wave per row; grid 128.
__global__ void k_feat(const float* __restrict__ projW, const float* __restrict__ projb,
                       const float* __restrict__ outff, float* __restrict__ feat) {
    int lane = threadIdx.x & 63;
    int j    = blockIdx.x * 4 + (threadIdx.x >> 6);
    const float4* row = reinterpret_cast<const float4*>(projW + (size_t)j * FEATN);
    const float4* v   = reinterpret_cast<const float4*>(outff);
    float4 a0 = row[lane],      b0 = v[lane];
    float4 a1 = row[lane + 64], b1 = v[lane + 64];
    float s = a0.x * b0.x + a0.y * b0.y + a0.z * b0.z + a0.w * b0.w
            + a1.x * b1.x + a1.y * b1.y + a1.z * b1.z + a1.w * b1.w;
    #pragma unroll
    for (int k = 32; k >= 1; k >>= 1) s += __shfl_xor(s, k, 64);
    if (lane == 0) {
        float f = s + projb[j];
        feat[j] = f > 0.f ? f : 0.f;
    }
}

// K6: d2[m] = ||som_w[m,:] - feat||^2, 8 rows/wave (16 dwordx4 in flight before
// any reduce). d2 -> d_out; grid argmin via encoded atomicMin. grid 2048, block 256.
__global__ void k_d2(const float* __restrict__ somw, const float* __restrict__ feat,
                     float* __restrict__ d2out, unsigned long long* __restrict__ bmuKey) {
    __shared__ float sf[FEATN];
    __shared__ unsigned long long smin[4];
    int tid = threadIdx.x;
    sf[tid]       = feat[tid];
    sf[tid + 256] = feat[tid + 256];
    __syncthreads();

    int wave = tid >> 6, lane = tid & 63;
    int base = blockIdx.x * 32 + wave * 8;
    const float4* fv = reinterpret_cast<const float4*>(sf);
    float4 f0 = fv[lane], f1 = fv[lane + 64];

    float4 va[8], vb[8];
    #pragma unroll
    for (int r = 0; r < 8; ++r) {
        const float4* row = reinterpret_cast<const float4*>(somw + (size_t)(base + r) * FEATN);
        va[r] = row[lane];
        vb[r] = row[lane + 64];
    }

    float s[8];
    #pragma unroll
    for (int r = 0; r < 8; ++r) {
        float d, acc = 0.f;
        d = va[r].x - f0.x; acc += d * d;
        d = va[r].y - f0.y; acc += d * d;
        d = va[r].z - f0.z; acc += d * d;
        d = va[r].w - f0.w; acc += d * d;
        d = vb[r].x - f1.x; acc += d * d;
        d = vb[r].y - f1.y; acc += d * d;
        d = vb[r].z - f1.z; acc += d * d;
        d = vb[r].w - f1.w; acc += d * d;
        s[r] = acc;
    }
    #pragma unroll
    for (int r = 0; r < 8; ++r) {
        #pragma unroll
        for (int k = 32; k >= 1; k >>= 1) s[r] += __shfl_xor(s[r], k, 64);
    }

    if (lane == 0) {
        *reinterpret_cast<float4*>(d2out + base)     = make_float4(s[0], s[1], s[2], s[3]);
        *reinterpret_cast<float4*>(d2out + base + 4) = make_float4(s[4], s[5], s[6], s[7]);
        unsigned long long kmin = ~0ull;
        #pragma unroll
        for (int r = 0; r < 8; ++r) {
            unsigned long long key =
                ((unsigned long long)__float_as_uint(s[r]) << 32) | (unsigned)(base + r);
            if (key < kmin) kmin = key;
        }
        smin[wave] = kmin;
    }
    __syncthreads();
    if (tid == 0) {
        unsigned long long k0 = smin[0];
        if (smin[1] < k0) k0 = smin[1];
        if (smin[2] < k0) k0 = smin[2];
        if (smin[3] < k0) k0 = smin[3];
        if (k0 < *(volatile unsigned long long*)bmuKey)
            atomicMin(bmuKey, k0);
    }
}

// K7: out[m] = exp(-d2[m]*(1-LR*nb(m))^6 / 1024). BMU invariant across the 3
// reference iterations (bmu's d2 shrinks by the strictly smallest factor).
__global__ void k_final(float* __restrict__ out, const unsigned long long* __restrict__ bmuKey) {
    int m = blockIdx.x * 256 + threadIdx.x;
    unsigned long long key = *bmuKey;
    int bmu = (int)(key & 0xFFFFFFFFull);
    float dy = (float)(m >> 8)  - (float)(bmu >> 8);
    float dx = (float)(m & 255) - (float)(bmu & 255);
    float g2 = dy * dy + dx * dx;
    float nb = expf(-g2 * 0.125f);          // 2*SIGMA^2 = 8
    float fac = 1.0f - LRC * nb;
    float f2 = fac * fac;
    float f6 = f2 * f2 * f2;                // 3 iterations -> (1-LR*nb)^6 on d2
    float d2 = out[m];
    out[m] = expf(-(d2 * f6) * (1.0f / 1024.0f));   // 2*FEAT = 1024
}

extern "C" void kernel_launch(void* const* d_in, const int* in_sizes, int n_in,
                              void* d_out, int out_size, void* d_ws, size_t ws_size,
                              hipStream_t stream) {
    (void)in_sizes; (void)n_in; (void)out_size; (void)ws_size;
    const float* sensory = (const float*)d_in[0];
    const float* Win     = (const float*)d_in[1];
    const float* Wout    = (const float*)d_in[2];
    const float* projW   = (const float*)d_in[3];
    const float* projb   = (const float*)d_in[4];
    const float* somw    = (const float*)d_in[5];
    float* out = (float*)d_out;

    char* ws = (char*)d_ws;
    float* sumx    = (float*)(ws);
    float* cur     = (float*)(ws + 16384);
    float* outff   = (float*)(ws + 18432);
    float* feat    = (float*)(ws + 20480);
    unsigned long long* bmuKey = (unsigned long long*)(ws + 22528);
    float* partial = (float*)(ws + 24576);

    hipLaunchKernelGGL(k_colsum,  dim3(4, CHUNKS), dim3(256), 0, stream,
                       sensory, partial, sumx, cur, outff, bmuKey);
    hipLaunchKernelGGL(k_fold,    dim3(16, 8),     dim3(256), 0, stream, partial, sumx);
    hipLaunchKernelGGL(k_current, dim3(64, 2),     dim3(256), 0, stream, Win, sumx, cur);
    hipLaunchKernelGGL(k_outff,   dim3(16, 2),     dim3(256), 0, stream, Wout, cur, outff);
    hipLaunchKernelGGL(k_feat,    dim3(128),       dim3(256), 0, stream, projW, projb, outff, feat);
    hipLaunchKernelGGL(k_d2,      dim3(2048),      dim3(256), 0, stream, somw, feat, out, bmuKey);
    hipLaunchKernelGGL(k_final,   dim3(256),       dim3(256), 0, stream, out, bmuKey);
}